// Round 1
// baseline (2266.912 us; speedup 1.0000x reference)
//
#include <hip/hip_runtime.h>
#include <math.h>

#define N_T 8000
#define N_D 6000
#define N_E 320000
#define N_B 16384

__device__ __forceinline__ float wave_sum(float v) {
  v += __shfl_xor(v, 32, 64);
  v += __shfl_xor(v, 16, 64);
  v += __shfl_xor(v, 8, 64);
  v += __shfl_xor(v, 4, 64);
  v += __shfl_xor(v, 2, 64);
  v += __shfl_xor(v, 1, 64);
  return v;
}

// ---------------- CSR build ----------------
__global__ void k_hist(const int* __restrict__ idx, int* __restrict__ cnt, int n) {
  int i = blockIdx.x * blockDim.x + threadIdx.x;
  if (i < n) atomicAdd(&cnt[idx[i]], 1);
}

__global__ void k_scan(const int* __restrict__ cnt, int* __restrict__ rp,
                       int* __restrict__ cur, int n) {
  __shared__ int buf[1024];
  __shared__ int carry_s;
  if (threadIdx.x == 0) carry_s = 0;
  __syncthreads();
  for (int base = 0; base < n; base += 1024) {
    int c0 = carry_s;
    int i = base + (int)threadIdx.x;
    int v = (i < n) ? cnt[i] : 0;
    buf[threadIdx.x] = v;
    __syncthreads();
    for (int off = 1; off < 1024; off <<= 1) {
      int t = (threadIdx.x >= (unsigned)off) ? buf[threadIdx.x - off] : 0;
      __syncthreads();
      buf[threadIdx.x] += t;
      __syncthreads();
    }
    int incl = buf[threadIdx.x];
    if (i < n) { int e = c0 + incl - v; rp[i] = e; cur[i] = e; }
    __syncthreads();
    if (threadIdx.x == 0) carry_s = c0 + buf[1023];
    __syncthreads();
  }
  if (threadIdx.x == 0) rp[n] = carry_s;
}

__global__ void k_scatter(const int* __restrict__ idx, int* __restrict__ cur,
                          int* __restrict__ perm, int n) {
  int i = blockIdx.x * blockDim.x + threadIdx.x;
  if (i < n) { int p = atomicAdd(&cur[idx[i]], 1); perm[p] = i; }
}

// ---------------- generic f32 GEMM ----------------
// TB=1: B is [N,K]  (C = A @ B^T) ;  TB=0: B is [K,N]  (C = A @ B)
// ACT: 0 none, 1 ELU, 2 ReLU.  BIAS: add bias[col].
template<int TB, int ACT, int BIAS>
__global__ __launch_bounds__(256) void k_gemm(const float* __restrict__ A,
    const float* __restrict__ B, const float* __restrict__ bias,
    float* __restrict__ C, int M, int N, int K) {
  __shared__ float As[16][65];
  __shared__ float Bs[16][65];
  const int tid = threadIdx.x;
  const int row0 = blockIdx.y * 64, col0 = blockIdx.x * 64;
  const int tr = tid >> 4, tc = tid & 15;
  float acc[4][4] = {};
  for (int k0 = 0; k0 < K; k0 += 16) {
    {
      int m = tid >> 2, kk = (tid & 3) * 4;
      int gr = row0 + m;
      float4 v = {0.f, 0.f, 0.f, 0.f};
      if (gr < M) v = *(const float4*)(A + (size_t)gr * K + k0 + kk);
      As[kk + 0][m] = v.x; As[kk + 1][m] = v.y; As[kk + 2][m] = v.z; As[kk + 3][m] = v.w;
    }
    if (TB) {
      int nn = tid >> 2, kk = (tid & 3) * 4;
      int gn = col0 + nn;
      float4 v = {0.f, 0.f, 0.f, 0.f};
      if (gn < N) v = *(const float4*)(B + (size_t)gn * K + k0 + kk);
      Bs[kk + 0][nn] = v.x; Bs[kk + 1][nn] = v.y; Bs[kk + 2][nn] = v.z; Bs[kk + 3][nn] = v.w;
    } else {
      int kk = tid >> 4, n4 = (tid & 15) * 4;
      int gn = col0 + n4;
      float4 v = {0.f, 0.f, 0.f, 0.f};
      if (gn < N) v = *(const float4*)(B + (size_t)(k0 + kk) * N + gn);
      Bs[kk][n4 + 0] = v.x; Bs[kk][n4 + 1] = v.y; Bs[kk][n4 + 2] = v.z; Bs[kk][n4 + 3] = v.w;
    }
    __syncthreads();
#pragma unroll
    for (int k = 0; k < 16; ++k) {
      float a[4], b[4];
#pragma unroll
      for (int i = 0; i < 4; ++i) a[i] = As[k][tr * 4 + i];
#pragma unroll
      for (int j = 0; j < 4; ++j) b[j] = Bs[k][tc * 4 + j];
#pragma unroll
      for (int i = 0; i < 4; ++i)
#pragma unroll
        for (int j = 0; j < 4; ++j)
          acc[i][j] = fmaf(a[i], b[j], acc[i][j]);
    }
    __syncthreads();
  }
#pragma unroll
  for (int i = 0; i < 4; ++i) {
    int gr = row0 + tr * 4 + i;
    if (gr >= M) continue;
#pragma unroll
    for (int j = 0; j < 4; ++j) {
      int gc = col0 + tc * 4 + j;
      if (gc >= N) continue;
      float v = acc[i][j];
      if (BIAS) v += bias[gc];
      if (ACT == 1) v = v > 0.f ? v : expm1f(v);
      if (ACT == 2) v = fmaxf(v, 0.f);
      C[(size_t)gr * N + gc] = v;
    }
  }
}

// ---------------- fused InfoNCE tile: exp(2*z1 z2^T), row-sums + diag ----------------
__global__ __launch_bounds__(256) void k_nce(const float* __restrict__ z1,
    const float* __restrict__ z2, float* __restrict__ rowsum,
    float* __restrict__ diagv, int M, int N) {
  __shared__ float As[16][65];
  __shared__ float Bs[16][65];
  const int tid = threadIdx.x;
  const int row0 = blockIdx.y * 64, col0 = blockIdx.x * 64;
  const int tr = tid >> 4, tc = tid & 15;
  float acc[4][4] = {};
  for (int k0 = 0; k0 < 128; k0 += 16) {
    {
      int m = tid >> 2, kk = (tid & 3) * 4;
      int gr = row0 + m;
      float4 v = {0.f, 0.f, 0.f, 0.f};
      if (gr < M) v = *(const float4*)(z1 + (size_t)gr * 128 + k0 + kk);
      As[kk + 0][m] = v.x; As[kk + 1][m] = v.y; As[kk + 2][m] = v.z; As[kk + 3][m] = v.w;
    }
    {
      int nn = tid >> 2, kk = (tid & 3) * 4;
      int gn = col0 + nn;
      float4 v = {0.f, 0.f, 0.f, 0.f};
      if (gn < N) v = *(const float4*)(z2 + (size_t)gn * 128 + k0 + kk);
      Bs[kk + 0][nn] = v.x; Bs[kk + 1][nn] = v.y; Bs[kk + 2][nn] = v.z; Bs[kk + 3][nn] = v.w;
    }
    __syncthreads();
#pragma unroll
    for (int k = 0; k < 16; ++k) {
      float a[4], b[4];
#pragma unroll
      for (int i = 0; i < 4; ++i) a[i] = As[k][tr * 4 + i];
#pragma unroll
      for (int j = 0; j < 4; ++j) b[j] = Bs[k][tc * 4 + j];
#pragma unroll
      for (int i = 0; i < 4; ++i)
#pragma unroll
        for (int j = 0; j < 4; ++j)
          acc[i][j] = fmaf(a[i], b[j], acc[i][j]);
    }
    __syncthreads();
  }
  float rs[4] = {0.f, 0.f, 0.f, 0.f};
#pragma unroll
  for (int i = 0; i < 4; ++i) {
    int gr = row0 + tr * 4 + i;
#pragma unroll
    for (int j = 0; j < 4; ++j) {
      int gc = col0 + tc * 4 + j;
      float sim = acc[i][j] * 2.0f;  // 1/TEMP
      if (gc < N) rs[i] += expf(sim);
      if (gr == gc && gr < M) diagv[gr] = sim;
    }
  }
#pragma unroll
  for (int i = 0; i < 4; ++i) {
    float v = rs[i];
    v += __shfl_xor(v, 1, 64);
    v += __shfl_xor(v, 2, 64);
    v += __shfl_xor(v, 4, 64);
    v += __shfl_xor(v, 8, 64);
    if (tc == 0) {
      int gr = row0 + tr * 4 + i;
      if (gr < M) atomicAdd(&rowsum[gr], v);
    }
  }
}

// ---------------- small helpers ----------------
// w[k] = sum_n W[n][k] * a[n]   (W is [128,128])
__global__ void k_matvec_col(const float* __restrict__ W, const float* __restrict__ a,
                             float* __restrict__ w) {
  int k = threadIdx.x;
  float s = 0.f;
  for (int n = 0; n < 128; ++n) s = fmaf(W[n * 128 + k], a[n], s);
  w[k] = s;
}

// out[r] = dot(h[r,:128], a[:128]); one wave per row
__global__ void k_rowdot(const float* __restrict__ h, const float* __restrict__ a,
                         float* __restrict__ out, int n) {
  int r = blockIdx.x * 4 + (threadIdx.x >> 6);
  int lane = threadIdx.x & 63;
  if (r >= n) return;
  float2 v = *(const float2*)(h + (size_t)r * 128 + lane * 2);
  float2 av = *(const float2*)(a + lane * 2);
  float s = v.x * av.x + v.y * av.y;
  s = wave_sum(s);
  if (lane == 0) out[r] = s;
}

__global__ void k_normalize(const float* __restrict__ x, float* __restrict__ z, int n) {
  int r = blockIdx.x * 4 + (threadIdx.x >> 6);
  int lane = threadIdx.x & 63;
  if (r >= n) return;
  float2 v = *(const float2*)(x + (size_t)r * 128 + lane * 2);
  float ss = v.x * v.x + v.y * v.y;
  ss = wave_sum(ss);
  float inv = 1.0f / (sqrtf(ss) + 1e-12f);
  float2 o; o.x = v.x * inv; o.y = v.y * inv;
  *(float2*)(z + (size_t)r * 128 + lane * 2) = o;
}

__global__ void k_edge(const float* __restrict__ si, const float* __restrict__ sj,
    const int* __restrict__ sidx, const int* __restrict__ tidx,
    float* __restrict__ expe, float* __restrict__ denom, int n) {
  int e = blockIdx.x * blockDim.x + threadIdx.x;
  if (e >= n) return;
  float v = si[sidx[e]] + sj[tidx[e]];
  v = v >= 0.f ? v : 0.2f * v;            // leaky_relu
  v = fminf(30.f, fmaxf(-30.f, v));       // clip
  float ev = expf(v);
  expe[e] = ev;
  atomicAdd(&denom[sidx[e]], ev);
}

__global__ __launch_bounds__(256) void k_aggregate(const int* __restrict__ rp,
    const int* __restrict__ perm, const int* __restrict__ nbr,
    const float* __restrict__ expe, const float* __restrict__ denom,
    const float* __restrict__ hj, float* __restrict__ out, int n) {
  int r = blockIdx.x * 2 + (threadIdx.x >> 7);
  int c = threadIdx.x & 127;
  if (r >= n) return;
  int p0 = rp[r], p1 = rp[r + 1];
  float acc = 0.f;
  for (int p = p0; p < p1; ++p) {
    int e = perm[p];
    acc = fmaf(expe[e], hj[(size_t)nbr[e] * 128 + c], acc);
  }
  acc *= 1.0f / (denom[r] + 1e-8f);
  out[(size_t)r * 128 + c] = acc > 0.f ? acc : expm1f(acc);
}

// C[256,128] += S^T @ x  over an m-chunk (atomic). S:[n,256], x:[n,128]
__global__ __launch_bounds__(256) void k_atb(const float* __restrict__ S,
    const float* __restrict__ x, float* __restrict__ C, int n) {
  int c = threadIdx.x & 127;
  int g = threadIdx.x >> 7;
  int h0 = blockIdx.x * 16 + g * 8;
  int nchunk = gridDim.y;
  int chunk = (n + nchunk - 1) / nchunk;
  int m0 = blockIdx.y * chunk, m1 = min(n, m0 + chunk);
  float acc[8] = {};
  for (int m = m0; m < m1; ++m) {
    float xv = x[(size_t)m * 128 + c];
    const float* Sr = S + (size_t)m * 256 + h0;
#pragma unroll
    for (int i = 0; i < 8; ++i) acc[i] = fmaf(Sr[i], xv, acc[i]);
  }
#pragma unroll
  for (int i = 0; i < 8; ++i) atomicAdd(&C[(size_t)(h0 + i) * 128 + c], acc[i]);
}

__global__ void k_gather(const float* __restrict__ sgt, const float* __restrict__ hgt,
    const float* __restrict__ sgd, const float* __restrict__ hgd,
    const int* __restrict__ tids, const int* __restrict__ dids,
    const float* __restrict__ gateW, float* __restrict__ mlp_in,
    float* __restrict__ gmf, float* __restrict__ gate_lin, int nB) {
  int b = blockIdx.x * 4 + (threadIdx.x >> 6);
  int lane = threadIdx.x & 63;
  if (b >= nB) return;
  int ti = tids[b], di = dids[b];
  float2 a1 = *(const float2*)(sgt + (size_t)ti * 128 + lane * 2);
  float2 a2 = *(const float2*)(hgt + (size_t)ti * 128 + lane * 2);
  float2 c1 = *(const float2*)(sgd + (size_t)di * 128 + lane * 2);
  float2 c2 = *(const float2*)(hgd + (size_t)di * 128 + lane * 2);
  float2 st; st.x = a1.x + a2.x; st.y = a1.y + a2.y;
  float2 sd; sd.x = c1.x + c2.x; sd.y = c1.y + c2.y;
  *(float2*)(mlp_in + (size_t)b * 256 + lane * 2) = st;
  *(float2*)(mlp_in + (size_t)b * 256 + 128 + lane * 2) = sd;
  float2 gv; gv.x = st.x * sd.x; gv.y = st.y * sd.y;
  float2 gw = *(const float2*)(gateW + lane * 2);
  float s1 = gv.x + gv.y;
  float s2 = gv.x * gw.x + gv.y * gw.y;
  s1 = wave_sum(s1);
  s2 = wave_sum(s2);
  if (lane == 0) { gmf[b] = s1; gate_lin[b] = s2; }
}

__global__ void k_final(const float* __restrict__ h1, const float* __restrict__ W2,
    const float* __restrict__ b2, const float* __restrict__ gate_lin,
    const float* __restrict__ gate_b, const float* __restrict__ gmf,
    float* __restrict__ fusion, float* __restrict__ mlp_pred, int nB) {
  int b = blockIdx.x * 4 + (threadIdx.x >> 6);
  int lane = threadIdx.x & 63;
  if (b >= nB) return;
  float2 hv = *(const float2*)(h1 + (size_t)b * 128 + lane * 2);
  float2 wv = *(const float2*)(W2 + lane * 2);
  float s = hv.x * wv.x + hv.y * wv.y;
  s = wave_sum(s);
  if (lane == 0) {
    float mp = s + b2[0];
    float g = 1.0f / (1.0f + expf(-(gate_lin[b] + gate_b[0])));
    mlp_pred[b] = mp;
    fusion[b] = g * gmf[b] + (1.0f - g) * mp;
  }
}

__global__ void k_contrast(const float* __restrict__ rs_t, const float* __restrict__ dg_t,
    const float* __restrict__ rs_d, const float* __restrict__ dg_d, float* __restrict__ out) {
  __shared__ float red[256];
  float st = 0.f, sd = 0.f;
  for (int i = threadIdx.x; i < N_T; i += 256) st += logf(rs_t[i]) - dg_t[i];
  for (int i = threadIdx.x; i < N_D; i += 256) sd += logf(rs_d[i]) - dg_d[i];
  red[threadIdx.x] = st * (1.0f / N_T) + sd * (1.0f / N_D);
  __syncthreads();
  for (int off = 128; off; off >>= 1) {
    if (threadIdx.x < (unsigned)off) red[threadIdx.x] += red[threadIdx.x + off];
    __syncthreads();
  }
  if (threadIdx.x == 0) out[0] = red[0];
}

// ---------------- host orchestration ----------------
extern "C" void kernel_launch(void* const* d_in, const int* in_sizes, int n_in,
                              void* d_out, int out_size, void* d_ws, size_t ws_size,
                              hipStream_t stream) {
  const float* trna   = (const float*)d_in[0];
  const float* dis    = (const float*)d_in[1];
  const float* thyper = (const float*)d_in[2];
  const float* dhyper = (const float*)d_in[3];
  const float* WsrcT  = (const float*)d_in[4];
  const float* WtgtT  = (const float*)d_in[5];
  const float* aT     = (const float*)d_in[6];
  const float* WsrcD  = (const float*)d_in[7];
  const float* WtgtD  = (const float*)d_in[8];
  const float* aD     = (const float*)d_in[9];
  const float* W1     = (const float*)d_in[10];
  const float* b1     = (const float*)d_in[11];
  const float* W2     = (const float*)d_in[12];
  const float* b2     = (const float*)d_in[13];
  const float* gW     = (const float*)d_in[14];
  const float* gb     = (const float*)d_in[15];
  const int* src_id   = (const int*)d_in[16];
  const int* tgt_id   = (const int*)d_in[17];
  const int* tids     = (const int*)d_in[18];
  const int* dids     = (const int*)d_in[19];
  float* out = (float*)d_out;

  float* out_fusion = out;
  float* out_sgt    = out + 16384;
  float* out_sgd    = out + 16384 + 1024000;
  float* out_gmf    = out + 1808384;
  float* out_mlp    = out + 1824768;
  float* out_con    = out + 1841152;

  char* wsb = (char*)d_ws;
  size_t off = 0;
  auto alloc = [&](size_t bytes) -> void* {
    void* p = wsb + off;
    off += (bytes + 255) & ~(size_t)255;
    return p;
  };
  float* sg_t   = (float*)alloc((size_t)N_T * 128 * 4);
  float* sg_d   = (float*)alloc((size_t)N_D * 128 * 4);
  float* hg_t   = (float*)alloc((size_t)N_T * 128 * 4);
  float* hg_d   = (float*)alloc((size_t)N_D * 128 * 4);
  float* hg_t3  = (float*)alloc((size_t)N_T * 128 * 4);
  float* hg_d3  = (float*)alloc((size_t)N_D * 128 * 4);
  float* h_i    = (float*)alloc((size_t)N_T * 128 * 4);  // also NCE z1
  float* h_j    = (float*)alloc((size_t)N_T * 128 * 4);  // also NCE z2
  float* Sbuf   = (float*)alloc((size_t)N_T * 256 * 4);
  float* M2     = (float*)alloc(256 * 128 * 4);
  float* s_i    = (float*)alloc(N_T * 4);
  float* s_j    = (float*)alloc(N_T * 4);
  float* denom  = (float*)alloc(N_T * 4);
  float* expe   = (float*)alloc((size_t)N_E * 4);
  float* wvec   = (float*)alloc(128 * 4);
  int* cnt_t    = (int*)alloc(N_T * 4);
  int* rp_t     = (int*)alloc((N_T + 1) * 4);
  int* cur_t    = (int*)alloc(N_T * 4);
  int* cnt_d    = (int*)alloc(N_D * 4);
  int* rp_d     = (int*)alloc((N_D + 1) * 4);
  int* cur_d    = (int*)alloc(N_D * 4);
  int* perm_t   = (int*)alloc((size_t)N_E * 4);
  int* perm_d   = (int*)alloc((size_t)N_E * 4);
  float* rs_t   = (float*)alloc(N_T * 4);
  float* dg_t   = (float*)alloc(N_T * 4);
  float* rs_d   = (float*)alloc(N_D * 4);
  float* dg_d   = (float*)alloc(N_D * 4);
  float* mlp_in = (float*)alloc((size_t)N_B * 256 * 4);
  float* h1buf  = (float*)alloc((size_t)N_B * 128 * 4);
  float* g_lin  = (float*)alloc(N_B * 4);
  (void)ws_size; (void)in_sizes; (void)n_in; (void)out_size;

  // CSR (t keyed by src_id, d keyed by tgt_id)
  hipMemsetAsync(cnt_t, 0, N_T * 4, stream);
  k_hist<<<(N_E + 255) / 256, 256, 0, stream>>>(src_id, cnt_t, N_E);
  k_scan<<<1, 1024, 0, stream>>>(cnt_t, rp_t, cur_t, N_T);
  k_scatter<<<(N_E + 255) / 256, 256, 0, stream>>>(src_id, cur_t, perm_t, N_E);
  hipMemsetAsync(cnt_d, 0, N_D * 4, stream);
  k_hist<<<(N_E + 255) / 256, 256, 0, stream>>>(tgt_id, cnt_d, N_E);
  k_scan<<<1, 1024, 0, stream>>>(cnt_d, rp_d, cur_d, N_D);
  k_scatter<<<(N_E + 255) / 256, 256, 0, stream>>>(tgt_id, cur_d, perm_d, N_E);

  auto run_gat = [&](const float* srcF, const float* tgtF, int ns, int nt,
                     const float* Wsrc, const float* Wtgt, const float* av,
                     const int* sidx, const int* tidx, const int* rp, const int* perm,
                     float* outF) {
    // s_i = srcF @ (Wsrc^T a[:128])  -- h_i never needed elsewhere
    k_matvec_col<<<1, 128, 0, stream>>>(Wsrc, av, wvec);
    k_rowdot<<<(ns + 3) / 4, 256, 0, stream>>>(srcF, wvec, s_i, ns);
    // h_j = tgtF @ Wtgt^T
    dim3 g2(2, (nt + 63) / 64);
    k_gemm<1, 0, 0><<<g2, 256, 0, stream>>>(tgtF, Wtgt, (const float*)nullptr, h_j, nt, 128, 128);
    k_rowdot<<<(nt + 3) / 4, 256, 0, stream>>>(h_j, av + 128, s_j, nt);
    hipMemsetAsync(denom, 0, ns * 4, stream);
    k_edge<<<(N_E + 255) / 256, 256, 0, stream>>>(s_i, s_j, sidx, tidx, expe, denom, N_E);
    k_aggregate<<<(ns + 1) / 2, 256, 0, stream>>>(rp, perm, tidx, expe, denom, h_j, outF, ns);
  };

  auto run_hg = [&](const float* x, const float* hyper, int n, float* outF) {
    dim3 gS(4, (n + 63) / 64);
    k_gemm<0, 0, 0><<<gS, 256, 0, stream>>>(x, hyper, (const float*)nullptr, Sbuf, n, 256, 128);
    hipMemsetAsync(M2, 0, 256 * 128 * 4, stream);
    dim3 gA(16, 25);
    k_atb<<<gA, 256, 0, stream>>>(Sbuf, x, M2, n);
    dim3 gO(2, (n + 63) / 64);
    k_gemm<0, 1, 0><<<gO, 256, 0, stream>>>(Sbuf, M2, (const float*)nullptr, outF, n, 128, 256);
  };

  // GAT layer 1
  run_gat(trna, dis, N_T, N_D, WsrcT, WtgtT, aT, src_id, tgt_id, rp_t, perm_t, sg_t);
  run_gat(dis, sg_t, N_D, N_T, WsrcD, WtgtD, aD, tgt_id, src_id, rp_d, perm_d, sg_d);
  // hypergraph passes 1-2 (in-place safe: final GEMM doesn't read x)
  run_hg(sg_t, thyper, N_T, hg_t);
  run_hg(sg_d, dhyper, N_D, hg_d);
  run_hg(hg_t, thyper, N_T, hg_t);
  run_hg(hg_d, dhyper, N_D, hg_d);
  // GAT layers 2-3
  run_gat(hg_t, hg_d, N_T, N_D, WsrcT + 16384, WtgtT + 16384, aT + 256, src_id, tgt_id, rp_t, perm_t, sg_t);
  run_gat(hg_d, hg_t, N_D, N_T, WsrcD + 16384, WtgtD + 16384, aD + 256, tgt_id, src_id, rp_d, perm_d, sg_d);
  run_gat(sg_t, sg_d, N_T, N_D, WsrcT + 32768, WtgtT + 32768, aT + 512, src_id, tgt_id, rp_t, perm_t, out_sgt);
  run_gat(sg_d, out_sgt, N_D, N_T, WsrcD + 32768, WtgtD + 32768, aD + 512, tgt_id, src_id, rp_d, perm_d, out_sgd);
  // hypergraph pass 3
  run_hg(hg_t, thyper, N_T, hg_t3);
  run_hg(hg_d, dhyper, N_D, hg_d3);

  // InfoNCE (sim in [-2,2] after /TEMP -> no max-shift needed)
  k_normalize<<<(N_T + 3) / 4, 256, 0, stream>>>(out_sgt, h_i, N_T);
  k_normalize<<<(N_T + 3) / 4, 256, 0, stream>>>(hg_t3, h_j, N_T);
  hipMemsetAsync(rs_t, 0, N_T * 4, stream);
  {
    dim3 g((N_T + 63) / 64, (N_T + 63) / 64);
    k_nce<<<g, 256, 0, stream>>>(h_i, h_j, rs_t, dg_t, N_T, N_T);
  }
  k_normalize<<<(N_D + 3) / 4, 256, 0, stream>>>(out_sgd, h_i, N_D);
  k_normalize<<<(N_D + 3) / 4, 256, 0, stream>>>(hg_d3, h_j, N_D);
  hipMemsetAsync(rs_d, 0, N_D * 4, stream);
  {
    dim3 g((N_D + 63) / 64, (N_D + 63) / 64);
    k_nce<<<g, 256, 0, stream>>>(h_i, h_j, rs_d, dg_d, N_D, N_D);
  }
  k_contrast<<<1, 256, 0, stream>>>(rs_t, dg_t, rs_d, dg_d, out_con);

  // prediction head
  k_gather<<<(N_B + 3) / 4, 256, 0, stream>>>(out_sgt, hg_t3, out_sgd, hg_d3,
      tids, dids, gW, mlp_in, out_gmf, g_lin, N_B);
  {
    dim3 g(2, (N_B + 63) / 64);
    k_gemm<1, 2, 1><<<g, 256, 0, stream>>>(mlp_in, W1, b1, h1buf, N_B, 128, 256);
  }
  k_final<<<(N_B + 3) / 4, 256, 0, stream>>>(h1buf, W2, b2, g_lin, gb,
      out_gmf, out_fusion, out_mlp, N_B);
}

// Round 2
// 1587.780 us; speedup vs baseline: 1.4277x; 1.4277x over previous
//
#include <hip/hip_runtime.h>
#include <math.h>

#define N_T 8000
#define N_D 6000
#define N_E 320000
#define N_B 16384

typedef __attribute__((ext_vector_type(8))) short s16x8;
typedef __attribute__((ext_vector_type(8))) __bf16 bf16x8;
typedef __attribute__((ext_vector_type(4))) float f32x4;

static __device__ __forceinline__ f32x4 mfma16(s16x8 a, s16x8 b, f32x4 c) {
  return __builtin_amdgcn_mfma_f32_16x16x32_bf16(
      __builtin_bit_cast(bf16x8, a), __builtin_bit_cast(bf16x8, b), c, 0, 0, 0);
}

static __device__ __forceinline__ unsigned short f2bf(float f) {
  unsigned u = __float_as_uint(f);
  u += 0x7FFF + ((u >> 16) & 1);
  return (unsigned short)(u >> 16);
}

__device__ __forceinline__ float wave_sum(float v) {
  v += __shfl_xor(v, 32, 64);
  v += __shfl_xor(v, 16, 64);
  v += __shfl_xor(v, 8, 64);
  v += __shfl_xor(v, 4, 64);
  v += __shfl_xor(v, 2, 64);
  v += __shfl_xor(v, 1, 64);
  return v;
}

// ---------------- CSR build ----------------
__global__ void k_hist(const int* __restrict__ idx, int* __restrict__ cnt, int n) {
  int i = blockIdx.x * blockDim.x + threadIdx.x;
  if (i < n) atomicAdd(&cnt[idx[i]], 1);
}

__global__ void k_scan(const int* __restrict__ cnt, int* __restrict__ rp,
                       int* __restrict__ cur, int n) {
  __shared__ int buf[1024];
  __shared__ int carry_s;
  if (threadIdx.x == 0) carry_s = 0;
  __syncthreads();
  for (int base = 0; base < n; base += 1024) {
    int c0 = carry_s;
    int i = base + (int)threadIdx.x;
    int v = (i < n) ? cnt[i] : 0;
    buf[threadIdx.x] = v;
    __syncthreads();
    for (int off = 1; off < 1024; off <<= 1) {
      int t = (threadIdx.x >= (unsigned)off) ? buf[threadIdx.x - off] : 0;
      __syncthreads();
      buf[threadIdx.x] += t;
      __syncthreads();
    }
    int incl = buf[threadIdx.x];
    if (i < n) { int e = c0 + incl - v; rp[i] = e; cur[i] = e; }
    __syncthreads();
    if (threadIdx.x == 0) carry_s = c0 + buf[1023];
    __syncthreads();
  }
  if (threadIdx.x == 0) rp[n] = carry_s;
}

__global__ void k_scatter(const int* __restrict__ idx, int* __restrict__ cur,
                          int* __restrict__ perm, int n) {
  int i = blockIdx.x * blockDim.x + threadIdx.x;
  if (i < n) { int p = atomicAdd(&cur[idx[i]], 1); perm[p] = i; }
}

// ---------------- small f32 GEMM (128-scale matrices only) ----------------
// C = A @ B^T, A:[M,K], B:[N,K]
__global__ __launch_bounds__(256) void k_gemm_f32(const float* __restrict__ A,
    const float* __restrict__ B, float* __restrict__ C, int M, int N, int K) {
  __shared__ float As[16][65];
  __shared__ float Bs[16][65];
  const int tid = threadIdx.x;
  const int row0 = blockIdx.y * 64, col0 = blockIdx.x * 64;
  const int tr = tid >> 4, tc = tid & 15;
  float acc[4][4] = {};
  for (int k0 = 0; k0 < K; k0 += 16) {
    {
      int m = tid >> 2, kk = (tid & 3) * 4;
      int gr = row0 + m;
      float4 v = {0.f, 0.f, 0.f, 0.f};
      if (gr < M) v = *(const float4*)(A + (size_t)gr * K + k0 + kk);
      As[kk + 0][m] = v.x; As[kk + 1][m] = v.y; As[kk + 2][m] = v.z; As[kk + 3][m] = v.w;
    }
    {
      int nn = tid >> 2, kk = (tid & 3) * 4;
      int gn = col0 + nn;
      float4 v = {0.f, 0.f, 0.f, 0.f};
      if (gn < N) v = *(const float4*)(B + (size_t)gn * K + k0 + kk);
      Bs[kk + 0][nn] = v.x; Bs[kk + 1][nn] = v.y; Bs[kk + 2][nn] = v.z; Bs[kk + 3][nn] = v.w;
    }
    __syncthreads();
#pragma unroll
    for (int k = 0; k < 16; ++k) {
      float a[4], b[4];
#pragma unroll
      for (int i = 0; i < 4; ++i) a[i] = As[k][tr * 4 + i];
#pragma unroll
      for (int j = 0; j < 4; ++j) b[j] = Bs[k][tc * 4 + j];
#pragma unroll
      for (int i = 0; i < 4; ++i)
#pragma unroll
        for (int j = 0; j < 4; ++j)
          acc[i][j] = fmaf(a[i], b[j], acc[i][j]);
    }
    __syncthreads();
  }
#pragma unroll
  for (int i = 0; i < 4; ++i) {
    int gr = row0 + tr * 4 + i;
    if (gr >= M) continue;
#pragma unroll
    for (int j = 0; j < 4; ++j) {
      int gc = col0 + tc * 4 + j;
      if (gc < N) C[(size_t)gr * N + gc] = acc[i][j];
    }
  }
}

// ---------------- f32 -> bf16 convert ----------------
__global__ void k_tobf16(const float* __restrict__ x, unsigned short* __restrict__ y, int n4) {
  int i = blockIdx.x * 256 + threadIdx.x;
  if (i >= n4) return;
  float4 v = ((const float4*)x)[i];
  ushort4 o;
  o.x = f2bf(v.x); o.y = f2bf(v.y); o.z = f2bf(v.z); o.w = f2bf(v.w);
  ((ushort4*)y)[i] = o;
}

// ---------------- bf16 MFMA GEMM: C = act(A @ B^T [+ bias]) ----------------
// A:[M,K] bf16, B:[N,K] bf16, C:[M,N] f32. K % 32 == 0. tile 128x128 (4 waves).
// ACT: 0 none, 1 ELU, 2 ReLU
template<int ACT, int BIAS>
__global__ __launch_bounds__(256) void k_mfma_gemm(const unsigned short* __restrict__ A,
    const unsigned short* __restrict__ B, const float* __restrict__ bias,
    float* __restrict__ C, int M, int N, int K) {
  const int wave = threadIdx.x >> 6, lane = threadIdx.x & 63;
  const int row0 = blockIdx.y * 128 + (wave >> 1) * 64;
  const int col0 = blockIdx.x * 128 + (wave & 1) * 64;
  const int l15 = lane & 15, kg = lane >> 4;
  f32x4 acc[4][4] = {};
  for (int k0 = 0; k0 < K; k0 += 32) {
    s16x8 a[4], b[4];
#pragma unroll
    for (int i = 0; i < 4; ++i) {
      int r = row0 + i * 16 + l15;
      a[i] = (r < M) ? *(const s16x8*)(A + (size_t)r * K + k0 + kg * 8) : (s16x8)0;
    }
#pragma unroll
    for (int j = 0; j < 4; ++j) {
      int c = col0 + j * 16 + l15;
      b[j] = (c < N) ? *(const s16x8*)(B + (size_t)c * K + k0 + kg * 8) : (s16x8)0;
    }
#pragma unroll
    for (int i = 0; i < 4; ++i)
#pragma unroll
      for (int j = 0; j < 4; ++j)
        acc[i][j] = mfma16(a[i], b[j], acc[i][j]);
  }
#pragma unroll
  for (int i = 0; i < 4; ++i) {
#pragma unroll
    for (int j = 0; j < 4; ++j) {
      int gc = col0 + j * 16 + l15;
      if (gc >= N) continue;
      float bv = BIAS ? bias[gc] : 0.f;
#pragma unroll
      for (int r = 0; r < 4; ++r) {
        int gr = row0 + i * 16 + kg * 4 + r;
        if (gr >= M) continue;
        float v = acc[i][j][r] + bv;
        if (ACT == 1) v = v > 0.f ? v : expm1f(v);
        if (ACT == 2) v = fmaxf(v, 0.f);
        C[(size_t)gr * N + gc] = v;
      }
    }
  }
}

// ---------------- fused NCE: rowsum(exp(2*z1 z2^T)) + diag, bf16 MFMA ----------------
__global__ __launch_bounds__(256) void k_nce_mfma(const unsigned short* __restrict__ z1,
    const unsigned short* __restrict__ z2, float* __restrict__ rowsum,
    float* __restrict__ diagv, int M, int N) {
  const int wave = threadIdx.x >> 6, lane = threadIdx.x & 63;
  const int row0 = blockIdx.y * 128 + (wave >> 1) * 64;
  const int col0 = blockIdx.x * 128 + (wave & 1) * 64;
  const int l15 = lane & 15, kg = lane >> 4;
  f32x4 acc[4][4] = {};
  for (int k0 = 0; k0 < 128; k0 += 32) {
    s16x8 a[4], b[4];
#pragma unroll
    for (int i = 0; i < 4; ++i) {
      int r = row0 + i * 16 + l15;
      a[i] = (r < M) ? *(const s16x8*)(z1 + (size_t)r * 128 + k0 + kg * 8) : (s16x8)0;
    }
#pragma unroll
    for (int j = 0; j < 4; ++j) {
      int c = col0 + j * 16 + l15;
      b[j] = (c < N) ? *(const s16x8*)(z2 + (size_t)c * 128 + k0 + kg * 8) : (s16x8)0;
    }
#pragma unroll
    for (int i = 0; i < 4; ++i)
#pragma unroll
      for (int j = 0; j < 4; ++j)
        acc[i][j] = mfma16(a[i], b[j], acc[i][j]);
  }
#pragma unroll
  for (int i = 0; i < 4; ++i) {
    float rs[4] = {0.f, 0.f, 0.f, 0.f};
#pragma unroll
    for (int j = 0; j < 4; ++j) {
      int gc = col0 + j * 16 + l15;
      bool cok = gc < N;
#pragma unroll
      for (int r = 0; r < 4; ++r) {
        float sim = acc[i][j][r] * 2.0f;   // 1/TEMP
        if (cok) rs[r] += expf(sim);
        int gr = row0 + i * 16 + kg * 4 + r;
        if (gr == gc && gr < M) diagv[gr] = sim;
      }
    }
#pragma unroll
    for (int r = 0; r < 4; ++r) {
      float v = rs[r];
      v += __shfl_xor(v, 1, 64);
      v += __shfl_xor(v, 2, 64);
      v += __shfl_xor(v, 4, 64);
      v += __shfl_xor(v, 8, 64);
      if (l15 == 0) {
        int gr = row0 + i * 16 + kg * 4 + r;
        if (gr < M) atomicAdd(&rowsum[gr], v);
      }
    }
  }
}

// ---------------- G = x^T x partials (split-K, 64 blocks) ----------------
__global__ __launch_bounds__(256) void k_syrk(const float* __restrict__ x,
    float* __restrict__ part, int n) {
  __shared__ float rows[4][128];
  int chunk = (n + 63) >> 6;
  int m0 = blockIdx.x * chunk, m1 = min(n, m0 + chunk);
  int tx = threadIdx.x & 15, ty = threadIdx.x >> 4;
  float acc[8][8] = {};
  for (int m = m0; m < m1; m += 4) {
    int nr = min(4, m1 - m);
    for (int t = threadIdx.x; t < nr * 128; t += 256)
      rows[t >> 7][t & 127] = x[(size_t)(m + (t >> 7)) * 128 + (t & 127)];
    __syncthreads();
    for (int r = 0; r < nr; ++r) {
      float a[8], b[8];
#pragma unroll
      for (int i = 0; i < 8; ++i) a[i] = rows[r][i * 16 + ty];
#pragma unroll
      for (int j = 0; j < 8; ++j) b[j] = rows[r][j * 16 + tx];
#pragma unroll
      for (int i = 0; i < 8; ++i)
#pragma unroll
        for (int j = 0; j < 8; ++j)
          acc[i][j] = fmaf(a[i], b[j], acc[i][j]);
    }
    __syncthreads();
  }
  float* p = part + (size_t)blockIdx.x * 16384;
#pragma unroll
  for (int i = 0; i < 8; ++i)
#pragma unroll
    for (int j = 0; j < 8; ++j)
      p[(i * 16 + ty) * 128 + j * 16 + tx] = acc[i][j];
}

__global__ void k_syrk_reduce(const float* __restrict__ part, float* __restrict__ G) {
  int i = blockIdx.x * 256 + threadIdx.x;
  float s = 0.f;
  for (int c = 0; c < 64; ++c) s += part[(size_t)c * 16384 + i];
  G[i] = s;
}

// ---------------- small helpers ----------------
__global__ void k_matvec_col(const float* __restrict__ W, const float* __restrict__ a,
                             float* __restrict__ w) {
  int k = threadIdx.x;
  float s = 0.f;
  for (int n = 0; n < 128; ++n) s = fmaf(W[n * 128 + k], a[n], s);
  w[k] = s;
}

__global__ void k_rowdot(const float* __restrict__ h, const float* __restrict__ a,
                         float* __restrict__ out, int n) {
  int r = blockIdx.x * 4 + (threadIdx.x >> 6);
  int lane = threadIdx.x & 63;
  if (r >= n) return;
  float2 v = *(const float2*)(h + (size_t)r * 128 + lane * 2);
  float2 av = *(const float2*)(a + lane * 2);
  float s = v.x * av.x + v.y * av.y;
  s = wave_sum(s);
  if (lane == 0) out[r] = s;
}

__global__ void k_normalize_bf(const float* __restrict__ x, unsigned short* __restrict__ z, int n) {
  int r = blockIdx.x * 4 + (threadIdx.x >> 6);
  int lane = threadIdx.x & 63;
  if (r >= n) return;
  float2 v = *(const float2*)(x + (size_t)r * 128 + lane * 2);
  float ss = v.x * v.x + v.y * v.y;
  ss = wave_sum(ss);
  float inv = 1.0f / (sqrtf(ss) + 1e-12f);
  ushort2 o;
  o.x = f2bf(v.x * inv); o.y = f2bf(v.y * inv);
  *(ushort2*)(z + (size_t)r * 128 + lane * 2) = o;
}

__global__ void k_edge(const float* __restrict__ si, const float* __restrict__ sj,
    const int* __restrict__ sidx, const int* __restrict__ tidx,
    float* __restrict__ expe, float* __restrict__ denom, int n) {
  int e = blockIdx.x * blockDim.x + threadIdx.x;
  if (e >= n) return;
  float v = si[sidx[e]] + sj[tidx[e]];
  v = v >= 0.f ? v : 0.2f * v;
  v = fminf(30.f, fmaxf(-30.f, v));
  float ev = expf(v);
  expe[e] = ev;
  atomicAdd(&denom[sidx[e]], ev);
}

__global__ __launch_bounds__(256) void k_aggregate(const int* __restrict__ rp,
    const int* __restrict__ perm, const int* __restrict__ nbr,
    const float* __restrict__ expe, const float* __restrict__ denom,
    const float* __restrict__ hj, float* __restrict__ out, int n) {
  int r = blockIdx.x * 2 + (threadIdx.x >> 7);
  int c = threadIdx.x & 127;
  if (r >= n) return;
  int p0 = rp[r], p1 = rp[r + 1];
  float acc = 0.f;
  for (int p = p0; p < p1; ++p) {
    int e = perm[p];
    acc = fmaf(expe[e], hj[(size_t)nbr[e] * 128 + c], acc);
  }
  acc *= 1.0f / (denom[r] + 1e-8f);
  out[(size_t)r * 128 + c] = acc > 0.f ? acc : expm1f(acc);
}

__global__ void k_gather(const float* __restrict__ sgt, const float* __restrict__ hgt,
    const float* __restrict__ sgd, const float* __restrict__ hgd,
    const int* __restrict__ tids, const int* __restrict__ dids,
    const float* __restrict__ gateW, unsigned short* __restrict__ mlp_in_b,
    float* __restrict__ gmf, float* __restrict__ gate_lin, int nB) {
  int b = blockIdx.x * 4 + (threadIdx.x >> 6);
  int lane = threadIdx.x & 63;
  if (b >= nB) return;
  int ti = tids[b], di = dids[b];
  float2 a1 = *(const float2*)(sgt + (size_t)ti * 128 + lane * 2);
  float2 a2 = *(const float2*)(hgt + (size_t)ti * 128 + lane * 2);
  float2 c1 = *(const float2*)(sgd + (size_t)di * 128 + lane * 2);
  float2 c2 = *(const float2*)(hgd + (size_t)di * 128 + lane * 2);
  float2 st; st.x = a1.x + a2.x; st.y = a1.y + a2.y;
  float2 sd; sd.x = c1.x + c2.x; sd.y = c1.y + c2.y;
  ushort2 o1; o1.x = f2bf(st.x); o1.y = f2bf(st.y);
  ushort2 o2; o2.x = f2bf(sd.x); o2.y = f2bf(sd.y);
  *(ushort2*)(mlp_in_b + (size_t)b * 256 + lane * 2) = o1;
  *(ushort2*)(mlp_in_b + (size_t)b * 256 + 128 + lane * 2) = o2;
  float2 gv; gv.x = st.x * sd.x; gv.y = st.y * sd.y;
  float2 gw = *(const float2*)(gateW + lane * 2);
  float s1 = gv.x + gv.y;
  float s2 = gv.x * gw.x + gv.y * gw.y;
  s1 = wave_sum(s1);
  s2 = wave_sum(s2);
  if (lane == 0) { gmf[b] = s1; gate_lin[b] = s2; }
}

__global__ void k_final(const float* __restrict__ h1, const float* __restrict__ W2,
    const float* __restrict__ b2, const float* __restrict__ gate_lin,
    const float* __restrict__ gate_b, const float* __restrict__ gmf,
    float* __restrict__ fusion, float* __restrict__ mlp_pred, int nB) {
  int b = blockIdx.x * 4 + (threadIdx.x >> 6);
  int lane = threadIdx.x & 63;
  if (b >= nB) return;
  float2 hv = *(const float2*)(h1 + (size_t)b * 128 + lane * 2);
  float2 wv = *(const float2*)(W2 + lane * 2);
  float s = hv.x * wv.x + hv.y * wv.y;
  s = wave_sum(s);
  if (lane == 0) {
    float mp = s + b2[0];
    float g = 1.0f / (1.0f + expf(-(gate_lin[b] + gate_b[0])));
    mlp_pred[b] = mp;
    fusion[b] = g * gmf[b] + (1.0f - g) * mp;
  }
}

__global__ void k_contrast(const float* __restrict__ rs_t, const float* __restrict__ dg_t,
    const float* __restrict__ rs_d, const float* __restrict__ dg_d, float* __restrict__ out) {
  __shared__ float red[256];
  float st = 0.f, sd = 0.f;
  for (int i = threadIdx.x; i < N_T; i += 256) st += logf(rs_t[i]) - dg_t[i];
  for (int i = threadIdx.x; i < N_D; i += 256) sd += logf(rs_d[i]) - dg_d[i];
  red[threadIdx.x] = st * (1.0f / N_T) + sd * (1.0f / N_D);
  __syncthreads();
  for (int off = 128; off; off >>= 1) {
    if (threadIdx.x < (unsigned)off) red[threadIdx.x] += red[threadIdx.x + off];
    __syncthreads();
  }
  if (threadIdx.x == 0) out[0] = red[0];
}

// ---------------- host orchestration ----------------
extern "C" void kernel_launch(void* const* d_in, const int* in_sizes, int n_in,
                              void* d_out, int out_size, void* d_ws, size_t ws_size,
                              hipStream_t stream) {
  const float* trna   = (const float*)d_in[0];
  const float* dis    = (const float*)d_in[1];
  const float* thyper = (const float*)d_in[2];
  const float* dhyper = (const float*)d_in[3];
  const float* WsrcT  = (const float*)d_in[4];
  const float* WtgtT  = (const float*)d_in[5];
  const float* aT     = (const float*)d_in[6];
  const float* WsrcD  = (const float*)d_in[7];
  const float* WtgtD  = (const float*)d_in[8];
  const float* aD     = (const float*)d_in[9];
  const float* W1     = (const float*)d_in[10];
  const float* b1     = (const float*)d_in[11];
  const float* W2     = (const float*)d_in[12];
  const float* b2     = (const float*)d_in[13];
  const float* gW     = (const float*)d_in[14];
  const float* gb     = (const float*)d_in[15];
  const int* src_id   = (const int*)d_in[16];
  const int* tgt_id   = (const int*)d_in[17];
  const int* tids     = (const int*)d_in[18];
  const int* dids     = (const int*)d_in[19];
  float* out = (float*)d_out;

  float* out_fusion = out;
  float* out_sgt    = out + 16384;
  float* out_sgd    = out + 16384 + 1024000;
  float* out_gmf    = out + 1808384;
  float* out_mlp    = out + 1824768;
  float* out_con    = out + 1841152;

  char* wsb = (char*)d_ws;
  size_t off = 0;
  auto alloc = [&](size_t bytes) -> void* {
    void* p = wsb + off;
    off += (bytes + 255) & ~(size_t)255;
    return p;
  };
  float* sg_t   = (float*)alloc((size_t)N_T * 128 * 4);
  float* sg_d   = (float*)alloc((size_t)N_D * 128 * 4);
  float* hg_t   = (float*)alloc((size_t)N_T * 128 * 4);
  float* hg_d   = (float*)alloc((size_t)N_D * 128 * 4);
  float* hg_t3  = (float*)alloc((size_t)N_T * 128 * 4);
  float* hg_d3  = (float*)alloc((size_t)N_D * 128 * 4);
  float* h_j    = (float*)alloc((size_t)N_T * 128 * 4);
  unsigned short* xb  = (unsigned short*)alloc((size_t)N_T * 128 * 2);
  unsigned short* zb1 = (unsigned short*)alloc((size_t)N_T * 128 * 2);
  unsigned short* zb2 = (unsigned short*)alloc((size_t)N_T * 128 * 2);
  unsigned short* wb  = (unsigned short*)alloc(16384 * 2);
  unsigned short* W1b = (unsigned short*)alloc(32768 * 2);
  unsigned short* mlp_in_b = (unsigned short*)alloc((size_t)N_B * 256 * 2);
  float* part   = (float*)alloc((size_t)64 * 16384 * 4);
  float* Gm     = (float*)alloc(16384 * 4);
  float* Wt     = (float*)alloc(16384 * 4);
  float* P_t    = (float*)alloc(16384 * 4);
  float* P_d    = (float*)alloc(16384 * 4);
  float* s_i    = (float*)alloc(N_T * 4);
  float* s_j    = (float*)alloc(N_T * 4);
  float* denom  = (float*)alloc(N_T * 4);
  float* expe   = (float*)alloc((size_t)N_E * 4);
  float* wvec   = (float*)alloc(128 * 4);
  int* cnt_t    = (int*)alloc(N_T * 4);
  int* rp_t     = (int*)alloc((N_T + 1) * 4);
  int* cur_t    = (int*)alloc(N_T * 4);
  int* cnt_d    = (int*)alloc(N_D * 4);
  int* rp_d     = (int*)alloc((N_D + 1) * 4);
  int* cur_d    = (int*)alloc(N_D * 4);
  int* perm_t   = (int*)alloc((size_t)N_E * 4);
  int* perm_d   = (int*)alloc((size_t)N_E * 4);
  float* rs_t   = (float*)alloc(N_T * 4);
  float* dg_t   = (float*)alloc(N_T * 4);
  float* rs_d   = (float*)alloc(N_D * 4);
  float* dg_d   = (float*)alloc(N_D * 4);
  float* h1buf  = (float*)alloc((size_t)N_B * 128 * 4);
  float* g_lin  = (float*)alloc(N_B * 4);
  (void)ws_size; (void)in_sizes; (void)n_in; (void)out_size;

  // CSR
  hipMemsetAsync(cnt_t, 0, N_T * 4, stream);
  k_hist<<<(N_E + 255) / 256, 256, 0, stream>>>(src_id, cnt_t, N_E);
  k_scan<<<1, 1024, 0, stream>>>(cnt_t, rp_t, cur_t, N_T);
  k_scatter<<<(N_E + 255) / 256, 256, 0, stream>>>(src_id, cur_t, perm_t, N_E);
  hipMemsetAsync(cnt_d, 0, N_D * 4, stream);
  k_hist<<<(N_E + 255) / 256, 256, 0, stream>>>(tgt_id, cnt_d, N_D > 0 ? N_E : N_E);
  k_scan<<<1, 1024, 0, stream>>>(cnt_d, rp_d, cur_d, N_D);
  k_scatter<<<(N_E + 255) / 256, 256, 0, stream>>>(tgt_id, cur_d, perm_d, N_E);

  // P = Hy @ Hy^T  (symmetric, 128x128)
  {
    dim3 g(2, 2);
    k_gemm_f32<<<g, 256, 0, stream>>>(thyper, thyper, P_t, 128, 128, 256);
    k_gemm_f32<<<g, 256, 0, stream>>>(dhyper, dhyper, P_d, 128, 128, 256);
  }

  auto run_gat = [&](const float* srcF, const float* tgtF, int ns, int nt,
                     const float* Wsrc, const float* Wtgt, const float* av,
                     const int* sidx, const int* tidx, const int* rp, const int* perm,
                     float* outF) {
    k_matvec_col<<<1, 128, 0, stream>>>(Wsrc, av, wvec);
    k_rowdot<<<(ns + 3) / 4, 256, 0, stream>>>(srcF, wvec, s_i, ns);
    k_tobf16<<<(nt * 32 + 255) / 256, 256, 0, stream>>>(tgtF, xb, nt * 32);
    k_tobf16<<<(4096 + 255) / 256, 256, 0, stream>>>(Wtgt, wb, 4096);
    dim3 gh(1, (nt + 127) / 128);
    k_mfma_gemm<0, 0><<<gh, 256, 0, stream>>>(xb, wb, (const float*)nullptr, h_j, nt, 128, 128);
    k_rowdot<<<(nt + 3) / 4, 256, 0, stream>>>(h_j, av + 128, s_j, nt);
    hipMemsetAsync(denom, 0, ns * 4, stream);
    k_edge<<<(N_E + 255) / 256, 256, 0, stream>>>(s_i, s_j, sidx, tidx, expe, denom, N_E);
    k_aggregate<<<(ns + 1) / 2, 256, 0, stream>>>(rp, perm, tidx, expe, denom, h_j, outF, ns);
  };

  // hypergraph pass: out = elu(x @ (P@G)) with G = x^T x; Wt = G@P = (P@G)^T
  auto run_hg = [&](const float* x, const float* P, int n, float* outF) {
    k_tobf16<<<(n * 32 + 255) / 256, 256, 0, stream>>>(x, xb, n * 32);
    k_syrk<<<64, 256, 0, stream>>>(x, part, n);
    k_syrk_reduce<<<64, 256, 0, stream>>>(part, Gm);
    dim3 gs(2, 2);
    k_gemm_f32<<<gs, 256, 0, stream>>>(Gm, P, Wt, 128, 128, 128);
    k_tobf16<<<(4096 + 255) / 256, 256, 0, stream>>>(Wt, wb, 4096);
    dim3 go(1, (n + 127) / 128);
    k_mfma_gemm<1, 0><<<go, 256, 0, stream>>>(xb, wb, (const float*)nullptr, outF, n, 128, 128);
  };

  // GAT layer 1
  run_gat(trna, dis, N_T, N_D, WsrcT, WtgtT, aT, src_id, tgt_id, rp_t, perm_t, sg_t);
  run_gat(dis, sg_t, N_D, N_T, WsrcD, WtgtD, aD, tgt_id, src_id, rp_d, perm_d, sg_d);
  // hypergraph passes 1-2
  run_hg(sg_t, P_t, N_T, hg_t);
  run_hg(sg_d, P_d, N_D, hg_d);
  run_hg(hg_t, P_t, N_T, hg_t);
  run_hg(hg_d, P_d, N_D, hg_d);
  // GAT layers 2-3
  run_gat(hg_t, hg_d, N_T, N_D, WsrcT + 16384, WtgtT + 16384, aT + 256, src_id, tgt_id, rp_t, perm_t, sg_t);
  run_gat(hg_d, hg_t, N_D, N_T, WsrcD + 16384, WtgtD + 16384, aD + 256, tgt_id, src_id, rp_d, perm_d, sg_d);
  run_gat(sg_t, sg_d, N_T, N_D, WsrcT + 32768, WtgtT + 32768, aT + 512, src_id, tgt_id, rp_t, perm_t, out_sgt);
  run_gat(sg_d, out_sgt, N_D, N_T, WsrcD + 32768, WtgtD + 32768, aD + 512, tgt_id, src_id, rp_d, perm_d, out_sgd);
  // hypergraph pass 3
  run_hg(hg_t, P_t, N_T, hg_t3);
  run_hg(hg_d, P_d, N_D, hg_d3);

  // InfoNCE (sim in [-2,2] -> no max-shift needed)
  k_normalize_bf<<<(N_T + 3) / 4, 256, 0, stream>>>(out_sgt, zb1, N_T);
  k_normalize_bf<<<(N_T + 3) / 4, 256, 0, stream>>>(hg_t3, zb2, N_T);
  hipMemsetAsync(rs_t, 0, N_T * 4, stream);
  {
    dim3 g((N_T + 127) / 128, (N_T + 127) / 128);
    k_nce_mfma<<<g, 256, 0, stream>>>(zb1, zb2, rs_t, dg_t, N_T, N_T);
  }
  k_normalize_bf<<<(N_D + 3) / 4, 256, 0, stream>>>(out_sgd, zb1, N_D);
  k_normalize_bf<<<(N_D + 3) / 4, 256, 0, stream>>>(hg_d3, zb2, N_D);
  hipMemsetAsync(rs_d, 0, N_D * 4, stream);
  {
    dim3 g((N_D + 127) / 128, (N_D + 127) / 128);
    k_nce_mfma<<<g, 256, 0, stream>>>(zb1, zb2, rs_d, dg_d, N_D, N_D);
  }
  k_contrast<<<1, 256, 0, stream>>>(rs_t, dg_t, rs_d, dg_d, out_con);

  // prediction head
  k_tobf16<<<(8192 + 255) / 256, 256, 0, stream>>>(W1, W1b, 8192);
  k_gather<<<(N_B + 3) / 4, 256, 0, stream>>>(out_sgt, hg_t3, out_sgd, hg_d3,
      tids, dids, gW, mlp_in_b, out_gmf, g_lin, N_B);
  {
    dim3 g(1, N_B / 128);
    k_mfma_gemm<2, 1><<<g, 256, 0, stream>>>(mlp_in_b, W1b, b1, h1buf, N_B, 128, 256);
  }
  k_final<<<(N_B + 3) / 4, 256, 0, stream>>>(h1buf, W2, b2, g_lin, gb,
      out_gmf, out_fusion, out_mlp, N_B);
}